// Round 9
// baseline (21.091 us; speedup 1.0000x reference)
//
#include <hip/hip_runtime.h>

#define NQ 10
#define NDEPTH 4
#define NR 16              // amplitudes per lane (2^4)

// One WAVE per batch element: 64 lanes x 16 complex amps = 1024 amplitudes.
// Flat index i = lane*16 + r. Qubit q <-> bit k = 9-q of i:
//   q 0..5  -> lane bit (5-q), xor mask M = 32 >> q
//   q 6..9  -> register bit (9-q)
// Exact-math restructuring (verified r7):
//  * ring-0 folded into analytic product init via j(i)=(i^(i>>1))^((i&1)*0x300)
//  * ring-3 removed by pushing Z_q through the CNOTs (parity-mask readout)
// NEW (r9): commuting RX gates fused PAIRWISE into 2-qubit XX rotations.
//   lane x reg pair: partners i^a, i^b, i^ab -> S[r^b] reuses the 32 lane
//   shuffles already fetched for mask a (reg gate rides free). 10 -> 5
//   serial stages/layer, DS ops/layer 192 -> 96.
// Gate impls = r7's proven set: DPP xor1/2/8, ds_swizzle xor4/16, bpermute 32.

__device__ __forceinline__ float xf(int i) { return __int_as_float(i); }
__device__ __forceinline__ int   fx(float f) { return __float_as_int(f); }

__device__ __forceinline__ float dpp_xor1(float v) {   // quad_perm [1,0,3,2]
    return xf(__builtin_amdgcn_update_dpp(fx(v), fx(v), 0xB1, 0xF, 0xF, true));
}
__device__ __forceinline__ float dpp_xor2(float v) {   // quad_perm [2,3,0,1]
    return xf(__builtin_amdgcn_update_dpp(fx(v), fx(v), 0x4E, 0xF, 0xF, true));
}
__device__ __forceinline__ float dpp_xor3(float v) {   // quad_perm [3,2,1,0]
    return xf(__builtin_amdgcn_update_dpp(fx(v), fx(v), 0x1B, 0xF, 0xF, true));
}
__device__ __forceinline__ float dpp_xor8(float v) {   // row_ror:8
    return xf(__builtin_amdgcn_update_dpp(fx(v), fx(v), 0x128, 0xF, 0xF, true));
}

template<int M>
__device__ __forceinline__ float lane_xor(float v, int addr32) {
    if constexpr (M == 1)       return dpp_xor1(v);
    else if constexpr (M == 2)  return dpp_xor2(v);
    else if constexpr (M == 8)  return dpp_xor8(v);
    else if constexpr (M == 4)  return xf(__builtin_amdgcn_ds_swizzle(fx(v), 0x101F));
    else if constexpr (M == 16) return xf(__builtin_amdgcn_ds_swizzle(fx(v), 0x401F));
    else                        return xf(__builtin_amdgcn_ds_bpermute(addr32, fx(v)));
}

// Fused RX(lane qubit a, mask LM) * RX(reg qubit b, reg-bit RB):
// out_re[r] = cc*re[r] + cs*im[r^RB] + sc*Sim[r] - ss*Sre[r^RB]
// out_im[r] = cc*im[r] - cs*re[r^RB] - sc*Sre[r] - ss*Sim[r^RB]
// where S* = lane-shuffle by LM (32 shuffles total, reg partner is free).
template<int LM, int RB>
__device__ __forceinline__ void rx2_lane_reg(float (&re)[NR], float (&im)[NR],
                                             float cc, float cs, float sc, float ss,
                                             int addr32) {
    float Sre[NR], Sim[NR];
    #pragma unroll
    for (int r = 0; r < NR; ++r) {
        Sre[r] = lane_xor<LM>(re[r], addr32);
        Sim[r] = lane_xor<LM>(im[r], addr32);
    }
    float nre[NR], nim[NR];
    #pragma unroll
    for (int r = 0; r < NR; ++r) {
        const int rb = r ^ RB;
        nre[r] = cc * re[r] + cs * im[rb] + sc * Sim[r] - ss * Sre[rb];
        nim[r] = cc * im[r] - cs * re[rb] - sc * Sre[r] - ss * Sim[rb];
    }
    #pragma unroll
    for (int r = 0; r < NR; ++r) { re[r] = nre[r]; im[r] = nim[r]; }
}

// Fused RX(q4, mask 2) * RX(q5, mask 1): all partners within a quad -> DPP only.
__device__ __forceinline__ void rx2_q45(float (&re)[NR], float (&im)[NR],
                                        float cc, float cs, float sc, float ss) {
    #pragma unroll
    for (int r = 0; r < NR; ++r) {
        const float r0 = re[r], i0 = im[r];
        const float S1r = dpp_xor1(r0), S1i = dpp_xor1(i0);
        const float S2r = dpp_xor2(r0), S2i = dpp_xor2(i0);
        const float S3r = dpp_xor3(r0), S3i = dpp_xor3(i0);
        re[r] = cc * r0 + cs * S1i + sc * S2i - ss * S3r;
        im[r] = cc * i0 - cs * S1r - sc * S2r - ss * S3i;
    }
}

__device__ __forceinline__ void cnot_ring(float (&re)[NR], float (&im)[NR],
                                          int lane, int jaddr, int addr32) {
    // CNOTs (0->1)...(4->5): composed lane permutation, one bpermute pass
    #pragma unroll
    for (int r = 0; r < NR; ++r) {
        re[r] = xf(__builtin_amdgcn_ds_bpermute(jaddr, fx(re[r])));
        im[r] = xf(__builtin_amdgcn_ds_bpermute(jaddr, fx(im[r])));
    }
    // C(5->6): ctrl lane bit0, tgt reg bit3 -> conditional reg swap
    const bool ctl = (lane & 1) != 0;
    #pragma unroll
    for (int r = 0; r < 8; ++r) {
        const float a0 = re[r], a1 = re[r + 8];
        re[r] = ctl ? a1 : a0;  re[r + 8] = ctl ? a0 : a1;
        const float b0 = im[r], b1 = im[r + 8];
        im[r] = ctl ? b1 : b0;  im[r + 8] = ctl ? b0 : b1;
    }
    // C(6->7): regs bit3=1 swap bit2
    #pragma unroll
    for (int r = 8; r < 12; ++r) {
        float t = re[r]; re[r] = re[r + 4]; re[r + 4] = t;
        t = im[r]; im[r] = im[r + 4]; im[r + 4] = t;
    }
    // C(7->8): regs bit2=1 swap bit1
    {
        const int rs[4] = {4, 5, 12, 13};
        #pragma unroll
        for (int k = 0; k < 4; ++k) {
            const int r = rs[k];
            float t = re[r]; re[r] = re[r + 2]; re[r + 2] = t;
            t = im[r]; im[r] = im[r + 2]; im[r + 2] = t;
        }
    }
    // C(8->9): regs bit1=1 swap bit0
    {
        const int rs[4] = {2, 6, 10, 14};
        #pragma unroll
        for (int k = 0; k < 4; ++k) {
            const int r = rs[k];
            float t = re[r]; re[r] = re[r + 1]; re[r + 1] = t;
            t = im[r]; im[r] = im[r + 1]; im[r + 1] = t;
        }
    }
    // C(9->0): ctrl reg bit0, tgt lane mask 32 -> bpermute odd regs
    #pragma unroll
    for (int r = 1; r < NR; r += 2) {
        re[r] = lane_xor<32>(re[r], addr32);
        im[r] = lane_xor<32>(im[r], addr32);
    }
}

__global__ __launch_bounds__(256, 2) void vql_kernel(
    const float* __restrict__ x,     // (B, NQ)
    const float* __restrict__ w,     // (NDEPTH, NQ)
    float* __restrict__ out,         // (B, NQ)
    int B)
{
    const int lane = threadIdx.x & 63;
    const int b = blockIdx.x * 4 + (threadIdx.x >> 6);
    if (b >= B) return;

    const int addr32 = (lane ^ 32) << 2;
    int j = lane;                       // composed C(0->1)..C(4->5) source lane
    j ^= ((j >> 1) & 1);
    j ^= ((j >> 2) & 1) << 1;
    j ^= ((j >> 3) & 1) << 2;
    j ^= ((j >> 4) & 1) << 3;
    j ^= ((j >> 5) & 1) << 4;
    const int jaddr = j << 2;

    // ---- per-batch angles (vectorized) ----
    const float2* xr = reinterpret_cast<const float2*>(x + b * NQ);
    const float2 x01 = xr[0], x23 = xr[1], x45 = xr[2], x67 = xr[3], x89 = xr[4];
    const float xa[NQ] = {0.5f * x01.x, 0.5f * x01.y, 0.5f * x23.x, 0.5f * x23.y,
                          0.5f * x45.x, 0.5f * x45.y, 0.5f * x67.x, 0.5f * x67.y,
                          0.5f * x89.x, 0.5f * x89.y};

    // ---- per-qubit factors: RX(w0q) RY(xq) |0> = (v0, v1) ----
    float v0r[NQ], v0i[NQ], v1r[NQ], v1i[NQ];
    #pragma unroll
    for (int q = 0; q < NQ; ++q) {
        float sy, cy, s, c;
        __sincosf(xa[q], &sy, &cy);
        __sincosf(0.5f * w[q], &s, &c);   // layer-0 weights
        v0r[q] = c * cy;  v0i[q] = -s * sy;
        v1r[q] = c * sy;  v1i[q] = -s * cy;
    }

    // ---- init = ring-0 applied to the product state, built DIRECTLY ----
    //   q0: L5^r0   q1: L4^L5^r0   q2: L3^L4   q3: L2^L3   q4: L1^L2
    //   q5: L0^L1   q6: r3^L0      q7: r2^r3   q8: r1^r2   q9: r0^r1
    const int L0 = lane & 1,        L1 = (lane >> 1) & 1, L2 = (lane >> 2) & 1;
    const int L3 = (lane >> 3) & 1, L4 = (lane >> 4) & 1, L5 = (lane >> 5) & 1;
    #define FR_(q,bit) ((bit) ? v1r[q] : v0r[q])
    #define FI_(q,bit) ((bit) ? v1i[q] : v0i[q])

    float Plr, Pli;     // f2*f3*f4*f5 (lane-only)
    {
        const int i2 = L3 ^ L4, i3 = L2 ^ L3, i4 = L1 ^ L2, i5 = L0 ^ L1;
        const float t1r = FR_(2,i2) * FR_(3,i3) - FI_(2,i2) * FI_(3,i3);
        const float t1i = FR_(2,i2) * FI_(3,i3) + FI_(2,i2) * FR_(3,i3);
        const float t2r = FR_(4,i4) * FR_(5,i5) - FI_(4,i4) * FI_(5,i5);
        const float t2i = FR_(4,i4) * FI_(5,i5) + FI_(4,i4) * FR_(5,i5);
        Plr = t1r * t2r - t1i * t2i;
        Pli = t1r * t2i + t1i * t2r;
    }
    float Ar[2], Ai[2];  // P_lane * f0(L5^r0) * f1(L4^L5^r0)
    #pragma unroll
    for (int r0 = 0; r0 < 2; ++r0) {
        const int i0 = L5 ^ r0, i1 = L4 ^ L5 ^ r0;
        const float ur = FR_(0,i0) * FR_(1,i1) - FI_(0,i0) * FI_(1,i1);
        const float ui = FR_(0,i0) * FI_(1,i1) + FI_(0,i0) * FR_(1,i1);
        Ar[r0] = Plr * ur - Pli * ui;
        Ai[r0] = Plr * ui + Pli * ur;
    }
    float Dr[2][2], Di[2][2];  // f6(r3^L0) * f7(r2^r3)
    #pragma unroll
    for (int r3 = 0; r3 < 2; ++r3)
        #pragma unroll
        for (int r2 = 0; r2 < 2; ++r2) {
            const int i6 = r3 ^ L0, i7 = r2 ^ r3;
            Dr[r3][r2] = FR_(6,i6) * FR_(7,i7) - FI_(6,i6) * FI_(7,i7);
            Di[r3][r2] = FR_(6,i6) * FI_(7,i7) + FI_(6,i6) * FR_(7,i7);
        }
    float Er[2][2], Ei[2][2];  // f8(a) * f9(bb)
    #pragma unroll
    for (int a = 0; a < 2; ++a)
        #pragma unroll
        for (int bb = 0; bb < 2; ++bb) {
            Er[a][bb] = FR_(8,a) * FR_(9,bb) - FI_(8,a) * FI_(9,bb);
            Ei[a][bb] = FR_(8,a) * FI_(9,bb) + FI_(8,a) * FR_(9,bb);
        }
    float re[NR], im[NR];
    #pragma unroll
    for (int r = 0; r < NR; ++r) {
        const int r3 = (r >> 3) & 1, r2 = (r >> 2) & 1, r1 = (r >> 1) & 1, r0 = r & 1;
        const float dr = Dr[r3][r2], di = Di[r3][r2];
        const float er = Er[r1 ^ r2][r0 ^ r1], ei = Ei[r1 ^ r2][r0 ^ r1];
        const float gr = dr * er - di * ei;
        const float gi = dr * ei + di * er;
        re[r] = Ar[r0] * gr - Ai[r0] * gi;
        im[r] = Ar[r0] * gi + Ai[r0] * gr;
    }
    #undef FR_
    #undef FI_

    // ---- layers 1..3: 5 fused 2-qubit stages each; ring after layers 1,2 ----
    #pragma unroll
    for (int l = 1; l < NDEPTH; ++l) {
        float c[NQ], s[NQ];
        #pragma unroll
        for (int q = 0; q < NQ; ++q)
            __sincosf(0.5f * w[l * NQ + q], &s[q], &c[q]);
        rx2_lane_reg<32, 8>(re, im, c[0]*c[6], c[0]*s[6], s[0]*c[6], s[0]*s[6], addr32);
        rx2_lane_reg<16, 4>(re, im, c[1]*c[7], c[1]*s[7], s[1]*c[7], s[1]*s[7], addr32);
        rx2_lane_reg< 8, 2>(re, im, c[2]*c[8], c[2]*s[8], s[2]*c[8], s[2]*s[8], addr32);
        rx2_lane_reg< 4, 1>(re, im, c[3]*c[9], c[3]*s[9], s[3]*c[9], s[3]*s[9], addr32);
        rx2_q45(re, im, c[4]*c[5], c[4]*s[5], s[4]*c[5], s[4]*s[5]);
        if (l < NDEPTH - 1)
            cnot_ring(re, im, lane, jaddr, addr32);
    }

    // ---- readout: parity-mask observables (ring-3 pushed through) ----
    float p[NR];
    #pragma unroll
    for (int r = 0; r < NR; ++r) p[r] = re[r] * re[r] + im[r] * im[r];

    float S0 = 0.f, S8 = 0.f, SC = 0.f, SE = 0.f, SF = 0.f;
    #pragma unroll
    for (int r = 0; r < NR; ++r) {
        const int b3 = (r >> 3) & 1, b2 = (r >> 2) & 1, b1 = (r >> 1) & 1, b0 = r & 1;
        S0 += p[r];
        S8 += (b3)                ? -p[r] : p[r];
        SC += (b3 ^ b2)           ? -p[r] : p[r];
        SE += (b3 ^ b2 ^ b1)      ? -p[r] : p[r];
        SF += (b3 ^ b2 ^ b1 ^ b0) ? -p[r] : p[r];
    }
    const float sg1F = (__builtin_popcount(lane & 0x1F) & 1) ? -1.f : 1.f;
    const float sg30 = (__builtin_popcount(lane & 0x30) & 1) ? -1.f : 1.f;
    const float sg38 = (__builtin_popcount(lane & 0x38) & 1) ? -1.f : 1.f;
    const float sg3C = (__builtin_popcount(lane & 0x3C) & 1) ? -1.f : 1.f;
    const float sg3E = (__builtin_popcount(lane & 0x3E) & 1) ? -1.f : 1.f;
    const float sg3F = (__builtin_popcount(lane & 0x3F) & 1) ? -1.f : 1.f;

    float z[NQ];
    z[0] = sg1F * SF;
    z[1] = sg30 * S0;
    z[2] = sg38 * S0;
    z[3] = sg3C * S0;
    z[4] = sg3E * S0;
    z[5] = sg3F * S0;
    z[6] = sg3F * S8;
    z[7] = sg3F * SC;
    z[8] = sg3F * SE;
    z[9] = sg3F * SF;

    #pragma unroll
    for (int q = 0; q < NQ; ++q) {
        z[q] += lane_xor<1>(z[q], addr32);
        z[q] += lane_xor<2>(z[q], addr32);
        z[q] += lane_xor<4>(z[q], addr32);
        z[q] += lane_xor<8>(z[q], addr32);
        z[q] += lane_xor<16>(z[q], addr32);
        z[q] += lane_xor<32>(z[q], addr32);
    }
    if (lane == 0) {
        #pragma unroll
        for (int q = 0; q < NQ; ++q) out[b * NQ + q] = z[q];
    }
}

extern "C" void kernel_launch(void* const* d_in, const int* in_sizes, int n_in,
                              void* d_out, int out_size, void* d_ws, size_t ws_size,
                              hipStream_t stream) {
    const float* x = (const float*)d_in[0];        // (BATCH, NQ) fp32
    const float* w = (const float*)d_in[1];        // (NDEPTH, NQ) fp32
    float* out = (float*)d_out;                    // (BATCH, NQ) fp32
    const int B = in_sizes[0] / NQ;
    vql_kernel<<<(B + 3) / 4, 256, 0, stream>>>(x, w, out, B);
}

// Round 10
// 18.152 us; speedup vs baseline: 1.1619x; 1.1619x over previous
//
#include <hip/hip_runtime.h>

#define NQ 10
#define NDEPTH 4
#define NR 16              // amplitudes per lane (2^4)

// One WAVE per batch element: 64 lanes x 16 complex amps = 1024 amplitudes.
// Flat index i = lane*16 + r. Qubit q <-> bit k = 9-q of i:
//   q 0..5  -> lane bit (5-q), xor mask M = 32 >> q
//   q 6..9  -> register bit (9-q)
// Exact-math restructuring (verified r7):
//  * ring-0 folded into analytic product init via j(i)=(i^(i>>1))^((i&1)*0x300)
//  * ring-3 removed by pushing Z_q through the CNOTs (parity-mask readout)
// r10 change (ONLY change vs r7): layer loop is ROLLED (#pragma unroll 1).
//   Hypothesis: the fully-unrolled kernel (~28 KB) thrashes the 32 KB L1 I$;
//   rolling shrinks code ~2.2x so the whole kernel fits.
// Gate impls = r7's proven set: DPP xor1/2/8, ds_swizzle xor4/16, bpermute 32.

__device__ __forceinline__ float xf(int i) { return __int_as_float(i); }
__device__ __forceinline__ int   fx(float f) { return __float_as_int(f); }

template<int M>
__device__ __forceinline__ float lane_xor(float v, int addr32) {
    if constexpr (M == 1)        // quad_perm [1,0,3,2]
        return xf(__builtin_amdgcn_update_dpp(fx(v), fx(v), 0xB1, 0xF, 0xF, true));
    else if constexpr (M == 2)   // quad_perm [2,3,0,1]
        return xf(__builtin_amdgcn_update_dpp(fx(v), fx(v), 0x4E, 0xF, 0xF, true));
    else if constexpr (M == 8)   // row_ror:8
        return xf(__builtin_amdgcn_update_dpp(fx(v), fx(v), 0x128, 0xF, 0xF, true));
    else if constexpr (M == 4)   // ds_swizzle bit-mode xor 4
        return xf(__builtin_amdgcn_ds_swizzle(fx(v), 0x101F));
    else if constexpr (M == 16)  // ds_swizzle bit-mode xor 16
        return xf(__builtin_amdgcn_ds_swizzle(fx(v), 0x401F));
    else                         // M == 32: bpermute, addr32 = (lane^32)<<2
        return xf(__builtin_amdgcn_ds_bpermute(addr32, fx(v)));
}

template<int M>
__device__ __forceinline__ void rx_lanebit(float (&re)[NR], float (&im)[NR],
                                           float c, float s, int addr32) {
    #pragma unroll
    for (int r = 0; r < NR; ++r) {
        const float pre = lane_xor<M>(re[r], addr32);
        const float pim = lane_xor<M>(im[r], addr32);
        re[r] = c * re[r] + s * pim;
        im[r] = c * im[r] - s * pre;
    }
}

template<int J>
__device__ __forceinline__ void rx_regbit(float (&re)[NR], float (&im)[NR],
                                          float c, float s) {
    #pragma unroll
    for (int r0 = 0; r0 < NR; ++r0) {
        if (r0 & (1 << J)) continue;
        const int r1 = r0 | (1 << J);
        const float R0 = re[r0], M0 = im[r0];
        const float R1 = re[r1], M1 = im[r1];
        re[r0] = c * R0 + s * M1;
        im[r0] = c * M0 - s * R1;
        re[r1] = c * R1 + s * M0;
        im[r1] = c * M1 - s * R0;
    }
}

__device__ __forceinline__ void cnot_ring(float (&re)[NR], float (&im)[NR],
                                          int lane, int jaddr, int addr32) {
    // CNOTs (0->1)...(4->5): composed lane permutation, one bpermute pass
    #pragma unroll
    for (int r = 0; r < NR; ++r) {
        re[r] = xf(__builtin_amdgcn_ds_bpermute(jaddr, fx(re[r])));
        im[r] = xf(__builtin_amdgcn_ds_bpermute(jaddr, fx(im[r])));
    }
    // C(5->6): ctrl lane bit0, tgt reg bit3 -> conditional reg swap
    const bool ctl = (lane & 1) != 0;
    #pragma unroll
    for (int r = 0; r < 8; ++r) {
        const float a0 = re[r], a1 = re[r + 8];
        re[r] = ctl ? a1 : a0;  re[r + 8] = ctl ? a0 : a1;
        const float b0 = im[r], b1 = im[r + 8];
        im[r] = ctl ? b1 : b0;  im[r + 8] = ctl ? b0 : b1;
    }
    // C(6->7): regs bit3=1 swap bit2
    #pragma unroll
    for (int r = 8; r < 12; ++r) {
        float t = re[r]; re[r] = re[r + 4]; re[r + 4] = t;
        t = im[r]; im[r] = im[r + 4]; im[r + 4] = t;
    }
    // C(7->8): regs bit2=1 swap bit1
    {
        const int rs[4] = {4, 5, 12, 13};
        #pragma unroll
        for (int k = 0; k < 4; ++k) {
            const int r = rs[k];
            float t = re[r]; re[r] = re[r + 2]; re[r + 2] = t;
            t = im[r]; im[r] = im[r + 2]; im[r + 2] = t;
        }
    }
    // C(8->9): regs bit1=1 swap bit0
    {
        const int rs[4] = {2, 6, 10, 14};
        #pragma unroll
        for (int k = 0; k < 4; ++k) {
            const int r = rs[k];
            float t = re[r]; re[r] = re[r + 1]; re[r + 1] = t;
            t = im[r]; im[r] = im[r + 1]; im[r + 1] = t;
        }
    }
    // C(9->0): ctrl reg bit0, tgt lane mask 32 -> bpermute odd regs
    #pragma unroll
    for (int r = 1; r < NR; r += 2) {
        re[r] = lane_xor<32>(re[r], addr32);
        im[r] = lane_xor<32>(im[r], addr32);
    }
}

__global__ __launch_bounds__(256, 2) void vql_kernel(
    const float* __restrict__ x,     // (B, NQ)
    const float* __restrict__ w,     // (NDEPTH, NQ)
    float* __restrict__ out,         // (B, NQ)
    int B)
{
    const int lane = threadIdx.x & 63;
    const int b = blockIdx.x * 4 + (threadIdx.x >> 6);
    if (b >= B) return;

    const int addr32 = (lane ^ 32) << 2;
    int j = lane;                       // composed C(0->1)..C(4->5) source lane
    j ^= ((j >> 1) & 1);
    j ^= ((j >> 2) & 1) << 1;
    j ^= ((j >> 3) & 1) << 2;
    j ^= ((j >> 4) & 1) << 3;
    j ^= ((j >> 5) & 1) << 4;
    const int jaddr = j << 2;

    // ---- per-batch angles (vectorized) ----
    const float2* xr = reinterpret_cast<const float2*>(x + b * NQ);
    const float2 x01 = xr[0], x23 = xr[1], x45 = xr[2], x67 = xr[3], x89 = xr[4];
    const float xa[NQ] = {0.5f * x01.x, 0.5f * x01.y, 0.5f * x23.x, 0.5f * x23.y,
                          0.5f * x45.x, 0.5f * x45.y, 0.5f * x67.x, 0.5f * x67.y,
                          0.5f * x89.x, 0.5f * x89.y};

    // ---- per-qubit factors: RX(w0q) RY(xq) |0> = (v0, v1) ----
    float v0r[NQ], v0i[NQ], v1r[NQ], v1i[NQ];
    #pragma unroll
    for (int q = 0; q < NQ; ++q) {
        float sy, cy, s, c;
        __sincosf(xa[q], &sy, &cy);
        __sincosf(0.5f * w[q], &s, &c);   // layer-0 weights
        v0r[q] = c * cy;  v0i[q] = -s * sy;
        v1r[q] = c * sy;  v1i[q] = -s * cy;
    }

    // ---- init = ring-0 applied to the product state, built DIRECTLY ----
    //   q0: L5^r0   q1: L4^L5^r0   q2: L3^L4   q3: L2^L3   q4: L1^L2
    //   q5: L0^L1   q6: r3^L0      q7: r2^r3   q8: r1^r2   q9: r0^r1
    const int L0 = lane & 1,        L1 = (lane >> 1) & 1, L2 = (lane >> 2) & 1;
    const int L3 = (lane >> 3) & 1, L4 = (lane >> 4) & 1, L5 = (lane >> 5) & 1;
    #define FR_(q,bit) ((bit) ? v1r[q] : v0r[q])
    #define FI_(q,bit) ((bit) ? v1i[q] : v0i[q])

    float Plr, Pli;     // f2*f3*f4*f5 (lane-only)
    {
        const int i2 = L3 ^ L4, i3 = L2 ^ L3, i4 = L1 ^ L2, i5 = L0 ^ L1;
        const float t1r = FR_(2,i2) * FR_(3,i3) - FI_(2,i2) * FI_(3,i3);
        const float t1i = FR_(2,i2) * FI_(3,i3) + FI_(2,i2) * FR_(3,i3);
        const float t2r = FR_(4,i4) * FR_(5,i5) - FI_(4,i4) * FI_(5,i5);
        const float t2i = FR_(4,i4) * FI_(5,i5) + FI_(4,i4) * FR_(5,i5);
        Plr = t1r * t2r - t1i * t2i;
        Pli = t1r * t2i + t1i * t2r;
    }
    float Ar[2], Ai[2];  // P_lane * f0(L5^r0) * f1(L4^L5^r0)
    #pragma unroll
    for (int r0 = 0; r0 < 2; ++r0) {
        const int i0 = L5 ^ r0, i1 = L4 ^ L5 ^ r0;
        const float ur = FR_(0,i0) * FR_(1,i1) - FI_(0,i0) * FI_(1,i1);
        const float ui = FR_(0,i0) * FI_(1,i1) + FI_(0,i0) * FR_(1,i1);
        Ar[r0] = Plr * ur - Pli * ui;
        Ai[r0] = Plr * ui + Pli * ur;
    }
    float Dr[2][2], Di[2][2];  // f6(r3^L0) * f7(r2^r3)
    #pragma unroll
    for (int r3 = 0; r3 < 2; ++r3)
        #pragma unroll
        for (int r2 = 0; r2 < 2; ++r2) {
            const int i6 = r3 ^ L0, i7 = r2 ^ r3;
            Dr[r3][r2] = FR_(6,i6) * FR_(7,i7) - FI_(6,i6) * FI_(7,i7);
            Di[r3][r2] = FR_(6,i6) * FI_(7,i7) + FI_(6,i6) * FR_(7,i7);
        }
    float Er[2][2], Ei[2][2];  // f8(a) * f9(bb)
    #pragma unroll
    for (int a = 0; a < 2; ++a)
        #pragma unroll
        for (int bb = 0; bb < 2; ++bb) {
            Er[a][bb] = FR_(8,a) * FR_(9,bb) - FI_(8,a) * FI_(9,bb);
            Ei[a][bb] = FR_(8,a) * FI_(9,bb) + FI_(8,a) * FR_(9,bb);
        }
    float re[NR], im[NR];
    #pragma unroll
    for (int r = 0; r < NR; ++r) {
        const int r3 = (r >> 3) & 1, r2 = (r >> 2) & 1, r1 = (r >> 1) & 1, r0 = r & 1;
        const float dr = Dr[r3][r2], di = Di[r3][r2];
        const float er = Er[r1 ^ r2][r0 ^ r1], ei = Ei[r1 ^ r2][r0 ^ r1];
        const float gr = dr * er - di * ei;
        const float gi = dr * ei + di * er;
        re[r] = Ar[r0] * gr - Ai[r0] * gi;
        im[r] = Ar[r0] * gi + Ai[r0] * gr;
    }
    #undef FR_
    #undef FI_

    // ---- layers 1..3: RX all qubits; ring only after layers 1,2 ----
    // ROLLED (r10): keep code resident in the 32 KB L1 I$.
    #pragma unroll 1
    for (int l = 1; l < NDEPTH; ++l) {
        float c[NQ], s[NQ];
        #pragma unroll
        for (int q = 0; q < NQ; ++q)
            __sincosf(0.5f * w[l * NQ + q], &s[q], &c[q]);
        rx_lanebit<32>(re, im, c[0], s[0], addr32);
        rx_lanebit<16>(re, im, c[1], s[1], addr32);
        rx_lanebit< 8>(re, im, c[2], s[2], addr32);
        rx_lanebit< 4>(re, im, c[3], s[3], addr32);
        rx_lanebit< 2>(re, im, c[4], s[4], addr32);
        rx_lanebit< 1>(re, im, c[5], s[5], addr32);
        rx_regbit<3>(re, im, c[6], s[6]);
        rx_regbit<2>(re, im, c[7], s[7]);
        rx_regbit<1>(re, im, c[8], s[8]);
        rx_regbit<0>(re, im, c[9], s[9]);
        if (l < NDEPTH - 1)
            cnot_ring(re, im, lane, jaddr, addr32);
    }

    // ---- readout: parity-mask observables (ring-3 pushed through) ----
    float p[NR];
    #pragma unroll
    for (int r = 0; r < NR; ++r) p[r] = re[r] * re[r] + im[r] * im[r];

    float S0 = 0.f, S8 = 0.f, SC = 0.f, SE = 0.f, SF = 0.f;
    #pragma unroll
    for (int r = 0; r < NR; ++r) {
        const int b3 = (r >> 3) & 1, b2 = (r >> 2) & 1, b1 = (r >> 1) & 1, b0 = r & 1;
        S0 += p[r];
        S8 += (b3)                ? -p[r] : p[r];
        SC += (b3 ^ b2)           ? -p[r] : p[r];
        SE += (b3 ^ b2 ^ b1)      ? -p[r] : p[r];
        SF += (b3 ^ b2 ^ b1 ^ b0) ? -p[r] : p[r];
    }
    const float sg1F = (__builtin_popcount(lane & 0x1F) & 1) ? -1.f : 1.f;
    const float sg30 = (__builtin_popcount(lane & 0x30) & 1) ? -1.f : 1.f;
    const float sg38 = (__builtin_popcount(lane & 0x38) & 1) ? -1.f : 1.f;
    const float sg3C = (__builtin_popcount(lane & 0x3C) & 1) ? -1.f : 1.f;
    const float sg3E = (__builtin_popcount(lane & 0x3E) & 1) ? -1.f : 1.f;
    const float sg3F = (__builtin_popcount(lane & 0x3F) & 1) ? -1.f : 1.f;

    float z[NQ];
    z[0] = sg1F * SF;
    z[1] = sg30 * S0;
    z[2] = sg38 * S0;
    z[3] = sg3C * S0;
    z[4] = sg3E * S0;
    z[5] = sg3F * S0;
    z[6] = sg3F * S8;
    z[7] = sg3F * SC;
    z[8] = sg3F * SE;
    z[9] = sg3F * SF;

    #pragma unroll
    for (int q = 0; q < NQ; ++q) {
        z[q] += lane_xor<1>(z[q], addr32);
        z[q] += lane_xor<2>(z[q], addr32);
        z[q] += lane_xor<4>(z[q], addr32);
        z[q] += lane_xor<8>(z[q], addr32);
        z[q] += lane_xor<16>(z[q], addr32);
        z[q] += lane_xor<32>(z[q], addr32);
    }
    if (lane == 0) {
        #pragma unroll
        for (int q = 0; q < NQ; ++q) out[b * NQ + q] = z[q];
    }
}

extern "C" void kernel_launch(void* const* d_in, const int* in_sizes, int n_in,
                              void* d_out, int out_size, void* d_ws, size_t ws_size,
                              hipStream_t stream) {
    const float* x = (const float*)d_in[0];        // (BATCH, NQ) fp32
    const float* w = (const float*)d_in[1];        // (NDEPTH, NQ) fp32
    float* out = (float*)d_out;                    // (BATCH, NQ) fp32
    const int B = in_sizes[0] / NQ;
    vql_kernel<<<(B + 3) / 4, 256, 0, stream>>>(x, w, out, B);
}